// Round 5
// baseline (712.584 us; speedup 1.0000x reference)
//
#include <hip/hip_runtime.h>

#define DIM 1536
#define NHEADS 12
#define HD 128
#define MAX_ATTN_WIN 5632
#define RMS_EPS 1e-6f
#define KWROWS 5632
#define NT_MAX 88            // KWROWS / 64
#define TILE_ELEMS 8192      // 64 * 128 ushorts per K/V tile
#define KSTEPS 48            // DIM / 32
#define AREG 4096            // ushorts per A region (64 x 32 x {hi,lo})
#define BREG 8192            // ushorts per B region (128 x 32 x {hi,lo})

typedef unsigned short ushortT;
typedef __bf16 bf16x8 __attribute__((ext_vector_type(8)));
typedef float f32x4 __attribute__((ext_vector_type(4)));
typedef ushortT ushx8 __attribute__((ext_vector_type(8)));

__device__ __forceinline__ ushortT bf16r(float x) {
    union { float f; unsigned u; } v; v.f = x;
    unsigned r = v.u + 0x7FFFu + ((v.u >> 16) & 1u);
    return (ushortT)(r >> 16);
}
__device__ __forceinline__ ushx8 pack8(float4 a, float4 b) {
    ushx8 u;
    u[0] = bf16r(a.x); u[1] = bf16r(a.y); u[2] = bf16r(a.z); u[3] = bf16r(a.w);
    u[4] = bf16r(b.x); u[5] = bf16r(b.y); u[6] = bf16r(b.z); u[7] = bf16r(b.w);
    return u;
}

// async global->LDS, 16B per lane. LDS dest must be wave-uniform base + lane*16.
__device__ __forceinline__ void gload_lds16(const void* g, void* l) {
    typedef const __attribute__((address_space(1))) unsigned int GU;
    typedef __attribute__((address_space(3))) unsigned int LU;
    __builtin_amdgcn_global_load_lds((GU*)(unsigned long long)g,
                                     (LU*)(unsigned long long)l, 16, 0, 0);
}

// ============ pack bodies: fp32 -> DMA-ready split-bf16 regions ============
__device__ __forceinline__ void pack_a_body(const float* __restrict__ X,
                                            ushortT* __restrict__ Ap,
                                            int M, int idx)
{
    int row = idx / 192, ch = idx - row * 192;
    int ks = ch >> 2, c = ch & 3;
    int mb = row >> 6, r = row & 63;
    ushx8 uh, ul;
    if (row < M) {
        const float* p = X + (size_t)row * DIM + (ch << 3);
        float4 a = *(const float4*)p;
        float4 b2 = *(const float4*)(p + 4);
        float xs[8] = {a.x, a.y, a.z, a.w, b2.x, b2.y, b2.z, b2.w};
        #pragma unroll
        for (int j = 0; j < 8; ++j) {
            ushortT hh = bf16r(xs[j]);
            union { unsigned u; float f; } w; w.u = ((unsigned)hh) << 16;
            uh[j] = hh; ul[j] = bf16r(xs[j] - w.f);
        }
    } else {
        #pragma unroll
        for (int j = 0; j < 8; ++j) { uh[j] = 0; ul[j] = 0; }
    }
    size_t base = (size_t)(mb * KSTEPS + ks) * AREG
                + r * 32 + ((c ^ ((r >> 1) & 3)) << 3);
    *(ushx8*)&Ap[base] = uh;
    *(ushx8*)&Ap[base + 2048] = ul;
}

__device__ __forceinline__ void pack_b_body(const float* __restrict__ W,
                                            ushortT* __restrict__ Bp, int idx)
{
    int row = idx / 192, ch = idx - row * 192;
    int ks = ch >> 2, c = ch & 3;
    int nb = row >> 7, rn = row & 127;
    const float* p = W + (size_t)row * DIM + (ch << 3);
    float4 a = *(const float4*)p;
    float4 b2 = *(const float4*)(p + 4);
    float xs[8] = {a.x, a.y, a.z, a.w, b2.x, b2.y, b2.z, b2.w};
    ushx8 uh, ul;
    #pragma unroll
    for (int j = 0; j < 8; ++j) {
        ushortT hh = bf16r(xs[j]);
        union { unsigned u; float f; } w; w.u = ((unsigned)hh) << 16;
        uh[j] = hh; ul[j] = bf16r(xs[j] - w.f);
    }
    size_t base = (size_t)(nb * KSTEPS + ks) * BREG
                + rn * 32 + ((c ^ ((rn >> 1) & 3)) << 3);
    *(ushx8*)&Bp[base] = uh;
    *(ushx8*)&Bp[base + 4096] = ul;
}

// pack1: x -> Ap, wq -> Bp0, wk -> Bp1 in one launch
__global__ __launch_bounds__(256)
void pack1_kernel(const float* __restrict__ x, const float* __restrict__ wq,
                  const float* __restrict__ wk,
                  ushortT* __restrict__ Ap, ushortT* __restrict__ Bp0,
                  ushortT* __restrict__ Bp1, int M, int gA, int gB)
{
    int b = blockIdx.x;
    if (b < gA) {
        pack_a_body(x, Ap, M, b * 256 + threadIdx.x);
    } else if (b < gA + gB) {
        pack_b_body(wq, Bp0, (b - gA) * 256 + threadIdx.x);
    } else {
        pack_b_body(wk, Bp1, (b - gA - gB) * 256 + threadIdx.x);
    }
}

// pack2: wv -> Bp0, wo -> Bp1 in one launch
__global__ __launch_bounds__(256)
void pack2_kernel(const float* __restrict__ wv, const float* __restrict__ wo,
                  ushortT* __restrict__ Bp0, ushortT* __restrict__ Bp1, int gB)
{
    int b = blockIdx.x;
    if (b < gB) pack_b_body(wv, Bp0, b * 256 + threadIdx.x);
    else        pack_b_body(wo, Bp1, (b - gB) * 256 + threadIdx.x);
}

// pack_a standalone (for o_buf after attn)
__global__ __launch_bounds__(256)
void pack_a_kernel(const float* __restrict__ X, ushortT* __restrict__ Ap,
                   int M, int Mpad)
{
    int idx = blockIdx.x * 256 + threadIdx.x;
    if (idx >= Mpad * 192) return;
    pack_a_body(X, Ap, M, idx);
}

// ============ fast split-bf16 GEMM body from packed A/B ============
// C = A(MxK) * B(NxK)^T + bias via Ah*Bh + Al*Bh + Ah*Bl. Tile 64x128, BK=32.
// DMA double-buffered staging, one barrier/kstep. 48 KB LDS -> 3 blocks/CU.
template<int MODE>   // 0: fp32 C + bias.  1: bf16 into swizzled tile-major vw
__device__ __forceinline__
void gemm_body(const ushortT* __restrict__ Ap, const ushortT* __restrict__ Bp,
               const float* __restrict__ bias, float* __restrict__ C,
               ushortT* __restrict__ vwout, int M, int nmb, int orig,
               const int* __restrict__ p_cs, const int* __restrict__ p_ge,
               const int* __restrict__ p_le,
               ushortT (*As)[AREG], ushortT (*Bs)[BREG])
{
    const int tid = threadIdx.x;
    const int wid = tid >> 6, lane = tid & 63;
    const int lo = lane & 15, hi = lane >> 4;
    const int wm = wid >> 1, wn = wid & 1;

    // bijective XCD swizzle, nb-major (orig&7 is XCD up to a constant rotation)
    const int nwg = nmb * (DIM / 128);
    const int xcd = orig & 7, linb = orig >> 3;
    const int qd = nwg >> 3, rr2 = nwg & 7;
    const int wg = (xcd < rr2 ? xcd * (qd + 1) : rr2 * (qd + 1) + (xcd - rr2) * qd) + linb;
    const int nb = wg / nmb, mb = wg - nb * nmb;
    const int m0 = mb << 6, n0 = nb << 7;

    f32x4 acc[2][4];
    #pragma unroll
    for (int i = 0; i < 2; ++i)
        #pragma unroll
        for (int j = 0; j < 4; ++j) acc[i][j] = (f32x4)(0.f);

    const ushortT* Asrc = Ap + (size_t)mb * (KSTEPS * AREG);
    const ushortT* Bsrc = Bp + (size_t)nb * (KSTEPS * BREG);
    const int lofs = lane << 3;
    const int aBase0 = (wid << 10) + lofs;
    const int aBase1 = aBase0 + 512;
    const int bBase  = (wid << 11) + lofs;

    gload_lds16(Asrc + aBase0, &As[0][aBase0]);
    gload_lds16(Asrc + aBase1, &As[0][aBase1]);
    #pragma unroll
    for (int i = 0; i < 4; ++i)
        gload_lds16(Bsrc + bBase + (i << 9), &Bs[0][bBase + (i << 9)]);

    const int cOff = ((hi ^ ((lo >> 1) & 3)) << 3);

    for (int ks = 0; ks < KSTEPS; ++ks) {
        const int b = ks & 1;
        __syncthreads();
        if (ks + 1 < KSTEPS) {
            const ushortT* as1 = Asrc + ((size_t)(ks + 1) << 12);
            const ushortT* bs1 = Bsrc + ((size_t)(ks + 1) << 13);
            gload_lds16(as1 + aBase0, &As[b ^ 1][aBase0]);
            gload_lds16(as1 + aBase1, &As[b ^ 1][aBase1]);
            #pragma unroll
            for (int i = 0; i < 4; ++i)
                gload_lds16(bs1 + bBase + (i << 9), &Bs[b ^ 1][bBase + (i << 9)]);
        }

        bf16x8 aH[2], aL[2];
        #pragma unroll
        for (int mf = 0; mf < 2; ++mf) {
            int r = (wm << 5) + (mf << 4) + lo;
            aH[mf] = *(const bf16x8*)&As[b][r * 32 + cOff];
            aL[mf] = *(const bf16x8*)&As[b][r * 32 + cOff + 2048];
        }
        #pragma unroll
        for (int nf = 0; nf < 4; ++nf) {
            int rn = (wn << 6) + (nf << 4) + lo;
            bf16x8 bH = *(const bf16x8*)&Bs[b][rn * 32 + cOff];
            bf16x8 bL = *(const bf16x8*)&Bs[b][rn * 32 + cOff + 4096];
            #pragma unroll
            for (int mf = 0; mf < 2; ++mf) {
                acc[mf][nf] = __builtin_amdgcn_mfma_f32_16x16x32_bf16(aH[mf], bH, acc[mf][nf], 0, 0, 0);
                acc[mf][nf] = __builtin_amdgcn_mfma_f32_16x16x32_bf16(aL[mf], bH, acc[mf][nf], 0, 0, 0);
                acc[mf][nf] = __builtin_amdgcn_mfma_f32_16x16x32_bf16(aH[mf], bL, acc[mf][nf], 0, 0, 0);
            }
        }
    }

    if (MODE == 0) {
        #pragma unroll
        for (int mf = 0; mf < 2; ++mf) {
            #pragma unroll
            for (int reg = 0; reg < 4; ++reg) {
                int gm = m0 + (wm << 5) + (mf << 4) + (hi << 2) + reg;
                if (gm < M) {
                    #pragma unroll
                    for (int nf = 0; nf < 4; ++nf) {
                        int gn = n0 + (wn << 6) + (nf << 4) + lo;
                        C[(size_t)gm * DIM + gn] = acc[mf][nf][reg] + bias[gn];
                    }
                }
            }
        }
    } else {
        const int S = M;
        const int local_end = p_le[0] + (p_cs[0] + S) - p_ge[0];
        int win_start = local_end - MAX_ATTN_WIN; if (win_start < 0) win_start = 0;
        const int vbase = (local_end - S) - win_start;
        #pragma unroll
        for (int mf = 0; mf < 2; ++mf) {
            #pragma unroll
            for (int reg = 0; reg < 4; ++reg) {
                int gm = m0 + (wm << 5) + (mf << 4) + (hi << 2) + reg;
                if (gm < M) {
                    #pragma unroll
                    for (int nf = 0; nf < 4; ++nf) {
                        int gn = n0 + (wn << 6) + (nf << 4) + lo;
                        int h2 = gn >> 7, d = gn & 127;
                        int pos = vbase + gm;
                        int tt = pos >> 6, w = pos & 63;
                        int swz = (((w >> 3) ^ (d & 7)) << 3) | (w & 7);
                        vwout[((size_t)h2 * NT_MAX + tt) * TILE_ELEMS + ((size_t)d << 6) + swz] =
                            bf16r(acc[mf][nf][reg] + bias[gn]);
                    }
                }
            }
        }
    }
}

// fused Q+K projection: blocks [0,nwg) -> Q, [nwg,2nwg) -> K (shared A panel in L2)
__global__ __launch_bounds__(256, 3)
void gemm_qk_kernel(const ushortT* __restrict__ Ap,
                    const ushortT* __restrict__ BpQ, const ushortT* __restrict__ BpK,
                    const float* __restrict__ bq, const float* __restrict__ bk,
                    float* __restrict__ Cq, float* __restrict__ Ck,
                    int M, int nmb, int nwg)
{
    __shared__ __align__(16) ushortT As[2][AREG];
    __shared__ __align__(16) ushortT Bs[2][BREG];
    int gid = (int)blockIdx.x;
    if (gid < nwg)
        gemm_body<0>(Ap, BpQ, bq, Cq, nullptr, M, nmb, gid, nullptr, nullptr, nullptr, As, Bs);
    else
        gemm_body<0>(Ap, BpK, bk, Ck, nullptr, M, nmb, gid - nwg, nullptr, nullptr, nullptr, As, Bs);
}

template<int MODE>
__global__ __launch_bounds__(256, 3)
void gemm_single_kernel(const ushortT* __restrict__ Ap, const ushortT* __restrict__ Bp,
                        const float* __restrict__ bias, float* __restrict__ C,
                        ushortT* __restrict__ vwout, int M, int nmb,
                        const int* __restrict__ p_cs, const int* __restrict__ p_ge,
                        const int* __restrict__ p_le)
{
    __shared__ __align__(16) ushortT As[2][AREG];
    __shared__ __align__(16) ushortT Bs[2][BREG];
    gemm_body<MODE>(Ap, Bp, bias, C, vwout, M, nmb, (int)blockIdx.x,
                    p_cs, p_ge, p_le, As, Bs);
}

// ============ fused RMSNorm + RoPE (in-place, one block per token) ============
__global__ __launch_bounds__(256)
void rmsnorm_rope_kernel(float* __restrict__ qbuf, float* __restrict__ kbuf,
                         const float* __restrict__ gq, const float* __restrict__ gk,
                         const float* __restrict__ theta,
                         const int* __restrict__ p_gh, const int* __restrict__ p_gw,
                         const int* __restrict__ p_cs, int S)
{
    const int s = blockIdx.x;
    float* row = ((blockIdx.y == 0) ? qbuf : kbuf) + (size_t)s * DIM;
    const float* g = (blockIdx.y == 0) ? gq : gk;
    const int tid = threadIdx.x;

    float v[6];
    #pragma unroll
    for (int i = 0; i < 6; ++i) v[i] = row[tid * 6 + i];
    float ss = 0.f;
    #pragma unroll
    for (int i = 0; i < 6; ++i) ss += v[i] * v[i];
    #pragma unroll
    for (int off = 32; off > 0; off >>= 1) ss += __shfl_xor(ss, off, 64);

    __shared__ float red[4];
    if ((tid & 63) == 0) red[tid >> 6] = ss;
    __syncthreads();
    float tot = red[0] + red[1] + red[2] + red[3];
    float rs = rsqrtf(tot * (1.0f / DIM) + RMS_EPS);

    const int H = p_gh[0], W = p_gw[0];
    const int fs = p_cs[0] / (H * W);
    const int fr = s / (H * W);
    const int rem = s - fr * (H * W);
    const int hh = rem / W;
    const int ww = rem - hh * W;

    #pragma unroll
    for (int pi = 0; pi < 3; ++pi) {
        int p = tid * 3 + pi;
        int j = p & 63;
        float xr = v[pi * 2]     * rs * g[tid * 6 + pi * 2];
        float xi = v[pi * 2 + 1] * rs * g[tid * 6 + pi * 2 + 1];
        int rowi = (j < 22) ? (fs + fr) : ((j < 43) ? hh : ww);
        float ang = theta[rowi * 64 + j];
        float sn, cs;
        sincosf(ang, &sn, &cs);
        row[tid * 6 + pi * 2]     = xr * cs - xi * sn;
        row[tid * 6 + pi * 2 + 1] = xr * sn + xi * cs;
    }
}

// ============ fused K window + cached-V pack ============
// y = [0,12): pack K head y.  y = [12,24): pack cached V head y-12.
__global__ __launch_bounds__(256)
void pack_kv_kernel(const float* __restrict__ cache_k, const float* __restrict__ k_lin,
                    const float* __restrict__ cache_v,
                    ushortT* __restrict__ kw, ushortT* __restrict__ vw,
                    const int* __restrict__ p_cs, const int* __restrict__ p_ge,
                    const int* __restrict__ p_le, int S)
{
    const int kt = blockIdx.x;
    const int local_end = p_le[0] + (p_cs[0] + S) - p_ge[0];
    int win_start = local_end - MAX_ATTN_WIN; if (win_start < 0) win_start = 0;
    const int L = local_end - win_start;
    const int cpart = (local_end - S) - win_start;

    if (blockIdx.y < NHEADS) {
        const int h = blockIdx.y;
        #pragma unroll
        for (int i = 0; i < 4; ++i) {
            int cid = (i << 8) + threadIdx.x;
            int r = cid >> 4, c = cid & 15;
            int pos = (kt << 6) + r;
            ushx8 u;
            if (pos < L) {
                const float* src = (pos < cpart)
                    ? &cache_k[(size_t)(win_start + pos) * DIM + h * HD + (c << 3)]
                    : &k_lin[(size_t)(pos - cpart) * DIM + h * HD + (c << 3)];
                float4 a = *(const float4*)src;
                float4 b = *(const float4*)(src + 4);
                u = pack8(a, b);
            } else {
                #pragma unroll
                for (int j = 0; j < 8; ++j) u[j] = 0;
            }
            *(ushx8*)&kw[(size_t)h * (KWROWS * HD) + (size_t)pos * HD + ((c ^ (r & 15)) << 3)] = u;
        }
    } else {
        const int h = blockIdx.y - NHEADS;
        const int tbase = kt << 6;
        if (tbase >= cpart && tbase + 64 <= L) return;   // fully gemm<1>-written

        __shared__ float tile[64 * 132];
        #pragma unroll
        for (int i = 0; i < 8; ++i) {
            int cid = (i << 8) + threadIdx.x;
            int r = cid >> 5, fc = cid & 31;
            int pos = tbase + r;
            float4 vv = (pos < cpart)
                ? *(const float4*)&cache_v[(size_t)(win_start + pos) * DIM + h * HD + (fc << 2)]
                : make_float4(0.f, 0.f, 0.f, 0.f);
            *(float4*)&tile[r * 132 + (fc << 2)] = vv;
        }
        __syncthreads();
        #pragma unroll
        for (int i = 0; i < 4; ++i) {
            int cid = (i << 8) + threadIdx.x;
            int d = cid >> 3, kc = cid & 7;
            int kglob = tbase + (kc << 3);
            ushx8 u;
            #pragma unroll
            for (int j = 0; j < 8; ++j)
                u[j] = bf16r(tile[((kc << 3) + j) * 132 + d]);
            size_t base = ((size_t)h * NT_MAX + kt) * TILE_ELEMS + ((size_t)d << 6)
                        + ((size_t)((kc ^ (d & 7)) << 3));
            if (kglob + 8 <= cpart) {
                *(ushx8*)&vw[base] = u;
            } else {
                #pragma unroll
                for (int j = 0; j < 8; ++j) {
                    int pos = kglob + j;
                    if (pos < cpart)      vw[base + j] = u[j];
                    else if (pos >= L)    vw[base + j] = 0;
                }
            }
        }
    }
}

// ============ MFMA flash attention v6: QBLK=128, 32 q-rows per wave ============
// Each bF/vF LDS read feeds TWO MFMAs (2 q-subtiles per wave) -> per-q LDS-read
// traffic halves vs v5. K single-buffered + mid-tile restage, V double-buffered,
// DMA staging, one drain barrier + one pure barrier per tile (v5 schedule).
// P round-trip aliases each wave's OWN K-DMA quarter: 32q x 64k bf16 = 2048 ush
// = exactly the wave's staged region. 48 KB LDS; ~160 VGPR -> 2 blocks/CU.
__global__ __launch_bounds__(256, 2)
void attn_mfma6_kernel(const float* __restrict__ q_lin,
                       const ushortT* __restrict__ kw, const ushortT* __restrict__ vw,
                       float* __restrict__ obuf,
                       const int* __restrict__ p_cs, const int* __restrict__ p_ge,
                       const int* __restrict__ p_le, int S, int nqb)
{
    __shared__ __align__(16) ushortT Ks[TILE_ELEMS];      // 16 KB single
    __shared__ __align__(16) ushortT Vs[2][TILE_ELEMS];   // 32 KB double

    const int tid = threadIdx.x;
    const int wid = tid >> 6, lane = tid & 63;
    const int lo = lane & 15, hi = lane >> 4;

    const int nwg = nqb * NHEADS;
    const int orig = (int)blockIdx.x;
    const int xcd = orig & 7, linb = orig >> 3;
    const int qd = nwg >> 3, rr = nwg & 7;
    const int wg = (xcd < rr ? xcd * (qd + 1) : rr * (qd + 1) + (xcd - rr) * qd) + linb;
    const int h = wg / nqb;
    const int q0 = (wg - h * nqb) << 7;

    const int local_end = p_le[0] + (p_cs[0] + S) - p_ge[0];
    int win_start = local_end - MAX_ATTN_WIN; if (win_start < 0) win_start = 0;
    const int L = local_end - win_start;
    const int ntiles = (L + 63) >> 6;

    // Q A-frags: 2 subtiles of 16 rows; m = lo, k = ks*32 + hi*8 + j
    bf16x8 aQ[2][4];
    #pragma unroll
    for (int sub = 0; sub < 2; ++sub) {
        int q = q0 + (wid << 5) + (sub << 4) + lo;
        if (q < S) {
            const float* qp = q_lin + (size_t)q * DIM + h * HD + (hi << 3);
            #pragma unroll
            for (int ks = 0; ks < 4; ++ks) {
                float4 a = *(const float4*)&qp[ks * 32];
                float4 b = *(const float4*)&qp[ks * 32 + 4];
                ushx8 u = pack8(a, b);
                aQ[sub][ks] = *(bf16x8*)&u;
            }
        } else {
            ushx8 z;
            #pragma unroll
            for (int j = 0; j < 8; ++j) z[j] = 0;
            #pragma unroll
            for (int ks = 0; ks < 4; ++ks) aQ[sub][ks] = *(bf16x8*)&z;
        }
    }

    f32x4 Oa[2][8];
    float lsum[2][4];
    #pragma unroll
    for (int sub = 0; sub < 2; ++sub) {
        #pragma unroll
        for (int i = 0; i < 8; ++i) Oa[sub][i] = (f32x4)(0.f);
        #pragma unroll
        for (int i = 0; i < 4; ++i) lsum[sub][i] = 0.f;
    }

    const ushortT* kwp = kw + (size_t)h * (NT_MAX * TILE_ELEMS);
    const ushortT* vwp = vw + (size_t)h * (NT_MAX * TILE_ELEMS);
    const float scale = 0.08838834764831845f;   // 1/sqrt(128)
    const int pbase = wid << 11;                // wave's own Ks quarter (2048 ush)
    const int sbase = (wid << 11) + (lane << 3);

    // prologue: stage K(0), V(0)
    #pragma unroll
    for (int i = 0; i < 4; ++i) {
        gload_lds16(kwp + sbase + (i << 9), &Ks[sbase + (i << 9)]);
        gload_lds16(vwp + sbase + (i << 9), &Vs[0][sbase + (i << 9)]);
    }

    for (int t = 0; t < ntiles; ++t) {
        const int b = t & 1;
        __syncthreads();   // A: drains K(t),V(t) DMAs for all waves

        // ---- S = Q K^T, both subtiles share each bF read ----
        f32x4 Sa[2][4];
        #pragma unroll
        for (int nt = 0; nt < 4; ++nt) { Sa[0][nt] = (f32x4)(0.f); Sa[1][nt] = (f32x4)(0.f); }
        #pragma unroll
        for (int nt = 0; nt < 4; ++nt) {
            const int kr = (nt << 4) + lo;
            #pragma unroll
            for (int ks = 0; ks < 4; ++ks) {
                bf16x8 bF = *(const bf16x8*)&Ks[kr * 128 + ((((ks << 2) + hi) ^ (kr & 15)) << 3)];
                Sa[0][nt] = __builtin_amdgcn_mfma_f32_16x16x32_bf16(aQ[0][ks], bF, Sa[0][nt], 0, 0, 0);
                Sa[1][nt] = __builtin_amdgcn_mfma_f32_16x16x32_bf16(aQ[1][ks], bF, Sa[1][nt], 0, 0, 0);
            }
        }

        __syncthreads();   // B: all waves' Ks reads done (nothing in vmcnt flight)

        // issue V(t+1) -> other half (covered by softmax+P+PV, drained at next A)
        if (t + 1 < ntiles) {
            const ushortT* vsrc = vwp + ((size_t)(t + 1) << 13);
            ushortT* vdst = &Vs[b ^ 1][0];
            #pragma unroll
            for (int i = 0; i < 4; ++i)
                gload_lds16(vsrc + sbase + (i << 9), vdst + sbase + (i << 9));
        }

        // ---- fixed-max softmax: p = exp(s*scale - 20); accumulate l ----
        const bool tail = (((t + 1) << 6) > L);
        #pragma unroll
        for (int sub = 0; sub < 2; ++sub) {
            #pragma unroll
            for (int nt = 0; nt < 4; ++nt) {
                #pragma unroll
                for (int reg = 0; reg < 4; ++reg) {
                    float sv = Sa[sub][nt][reg] * scale - 20.f;
                    if (tail) {
                        int kg = (t << 6) + (nt << 4) + lo;
                        if (kg >= L) sv = -1e30f;
                    }
                    float p = __expf(sv);
                    lsum[sub][reg] += p;
                    Sa[sub][nt][reg] = p;
                }
            }
        }

        // ---- P round-trip via OWN Ks quarter (same-wave DS ordered) ----
        #pragma unroll
        for (int sub = 0; sub < 2; ++sub) {
            #pragma unroll
            for (int nt = 0; nt < 4; ++nt) {
                #pragma unroll
                for (int reg = 0; reg < 4; ++reg) {
                    int r = (hi << 2) + reg;
                    int cc = (nt << 1) + (lo >> 3);
                    Ks[pbase + (sub << 10) + (r << 6) + ((cc ^ (r & 7)) << 3) + (lo & 7)] =
                        bf16r(Sa[sub][nt][reg]);
                }
            }
        }
        bf16x8 pF[2][2];
        #pragma unroll
        for (int sub = 0; sub < 2; ++sub)
            #pragma unroll
            for (int ks = 0; ks < 2; ++ks)
                pF[sub][ks] = *(const bf16x8*)&Ks[pbase + (sub << 10) + (lo << 6)
                                                 + ((((ks << 2) + hi) ^ (lo & 7)) << 3)];

        // P data must be in registers before our K-DMA overwrites the quarter
        asm volatile("s_waitcnt lgkmcnt(0)" ::: "memory");
        __builtin_amdgcn_sched_barrier(0);

        // issue K(t+1) into own quarter (covered by PV, drained at next A)
        if (t + 1 < ntiles) {
            const ushortT* ksrc = kwp + ((size_t)(t + 1) << 13);
            #pragma unroll
            for (int i = 0; i < 4; ++i)
                gload_lds16(ksrc + sbase + (i << 9), &Ks[sbase + (i << 9)]);
        }

        // ---- O += P V, both subtiles share each vF read ----
        #pragma unroll
        for (int nto = 0; nto < 8; ++nto) {
            const int d = (nto << 4) + lo;
            #pragma unroll
            for (int ks = 0; ks < 2; ++ks) {
                bf16x8 vF = *(const bf16x8*)&Vs[b][(d << 6) + ((((ks << 2) + hi) ^ (d & 7)) << 3)];
                Oa[0][nto] = __builtin_amdgcn_mfma_f32_16x16x32_bf16(pF[0][ks], vF, Oa[0][nto], 0, 0, 0);
                Oa[1][nto] = __builtin_amdgcn_mfma_f32_16x16x32_bf16(pF[1][ks], vF, Oa[1][nto], 0, 0, 0);
            }
        }
    }

    #pragma unroll
    for (int sub = 0; sub < 2; ++sub) {
        #pragma unroll
        for (int reg = 0; reg < 4; ++reg) {
            #pragma unroll
            for (int off = 1; off < 16; off <<= 1)
                lsum[sub][reg] += __shfl_xor(lsum[sub][reg], off, 64);
        }
        #pragma unroll
        for (int reg = 0; reg < 4; ++reg) {
            int q = q0 + (wid << 5) + (sub << 4) + (hi << 2) + reg;
            if (q < S) {
                float inv = 1.f / lsum[sub][reg];
                #pragma unroll
                for (int nto = 0; nto < 8; ++nto)
                    obuf[(size_t)q * DIM + h * HD + (nto << 4) + lo] = Oa[sub][nto][reg] * inv;
            }
        }
    }
}

// ==================== launch ====================
extern "C" void kernel_launch(void* const* d_in, const int* in_sizes, int n_in,
                              void* d_out, int out_size, void* d_ws, size_t ws_size,
                              hipStream_t stream)
{
    const float* x       = (const float*)d_in[0];
    const float* theta   = (const float*)d_in[1];
    const float* cache_k = (const float*)d_in[2];
    const float* cache_v = (const float*)d_in[3];
    const float* wq = (const float*)d_in[4];
    const float* bq = (const float*)d_in[5];
    const float* wk = (const float*)d_in[6];
    const float* bk = (const float*)d_in[7];
    const float* wv = (const float*)d_in[8];
    const float* bv = (const float*)d_in[9];
    const float* wo = (const float*)d_in[10];
    const float* bo = (const float*)d_in[11];
    const float* gq = (const float*)d_in[12];
    const float* gk = (const float*)d_in[13];
    const int* p_gh = (const int*)d_in[15];
    const int* p_gw = (const int*)d_in[16];
    const int* p_cs = (const int*)d_in[17];
    const int* p_ge = (const int*)d_in[18];
    const int* p_le = (const int*)d_in[19];

    const int S = in_sizes[0] / DIM;
    const int nmb = (S + 63) / 64;                   // 49
    const int Mpad = nmb * 64;

    float* q_lin = (float*)d_ws;
    float* k_lin = q_lin + (size_t)S * DIM;
    float* o_buf = k_lin;
    ushortT* Ap  = (ushortT*)(k_lin + (size_t)S * DIM);
    ushortT* kw  = Ap;                                 // alias (Ap dead when kw written)
    ushortT* vw  = Ap + (size_t)nmb * KSTEPS * AREG;
    ushortT* Bp0 = vw + (size_t)NHEADS * NT_MAX * TILE_ELEMS;
    ushortT* Bp1 = Bp0 + (size_t)NHEADS * KSTEPS * BREG;

    dim3 blk(256);
    const int nwgG = nmb * (DIM / 128);                // 588
    const int gA = (Mpad * 192) / 256;                 // 2352
    const int gB = (DIM * 192) / 256;                  // 1152

    pack1_kernel<<<gA + 2 * gB, blk, 0, stream>>>(x, wq, wk, Ap, Bp0, Bp1, S, gA, gB);
    gemm_qk_kernel<<<2 * nwgG, blk, 0, stream>>>(Ap, Bp0, Bp1, bq, bk,
                                                 q_lin, k_lin, S, nmb, nwgG);
    pack2_kernel<<<2 * gB, blk, 0, stream>>>(wv, wo, Bp0, Bp1, gB);
    gemm_single_kernel<1><<<nwgG, blk, 0, stream>>>(Ap, Bp0, bv, nullptr, vw,
                                                    S, nmb, p_cs, p_ge, p_le);

    rmsnorm_rope_kernel<<<dim3(S, 2), blk, 0, stream>>>(q_lin, k_lin, gq, gk, theta,
                                                        p_gh, p_gw, p_cs, S);

    pack_kv_kernel<<<dim3(NT_MAX, 2 * NHEADS), blk, 0, stream>>>(
        cache_k, k_lin, cache_v, kw, vw, p_cs, p_ge, p_le, S);

    const int nqb = (S + 127) / 128;                   // 25
    attn_mfma6_kernel<<<dim3(nqb * NHEADS), blk, 0, stream>>>(
        q_lin, kw, vw, o_buf, p_cs, p_ge, p_le, S, nqb);

    pack_a_kernel<<<gA, blk, 0, stream>>>(o_buf, Ap, S, Mpad);
    gemm_single_kernel<0><<<nwgG, blk, 0, stream>>>(Ap, Bp1, bo, (float*)d_out, nullptr,
                                                    S, nmb, p_cs, p_ge, p_le);
}

// Round 6
// 671.694 us; speedup vs baseline: 1.0609x; 1.0609x over previous
//
#include <hip/hip_runtime.h>

#define DIM 1536
#define NHEADS 12
#define HD 128
#define MAX_ATTN_WIN 5632
#define RMS_EPS 1e-6f
#define KWROWS 5632
#define NT_MAX 88            // KWROWS / 64
#define TILE_ELEMS 8192      // 64 * 128 ushorts per K/V tile
#define KSTEPS 48            // DIM / 32
#define AREG 4096            // ushorts per A region (64 x 32 x {hi,lo})
#define BREG 8192            // ushorts per B region (128 x 32 x {hi,lo})

typedef unsigned short ushortT;
typedef __bf16 bf16x8 __attribute__((ext_vector_type(8)));
typedef float f32x4 __attribute__((ext_vector_type(4)));
typedef ushortT ushx8 __attribute__((ext_vector_type(8)));

__device__ __forceinline__ ushortT bf16r(float x) {
    union { float f; unsigned u; } v; v.f = x;
    unsigned r = v.u + 0x7FFFu + ((v.u >> 16) & 1u);
    return (ushortT)(r >> 16);
}
__device__ __forceinline__ ushx8 pack8(float4 a, float4 b) {
    ushx8 u;
    u[0] = bf16r(a.x); u[1] = bf16r(a.y); u[2] = bf16r(a.z); u[3] = bf16r(a.w);
    u[4] = bf16r(b.x); u[5] = bf16r(b.y); u[6] = bf16r(b.z); u[7] = bf16r(b.w);
    return u;
}

// async global->LDS, 16B per lane. LDS dest must be wave-uniform base + lane*16.
__device__ __forceinline__ void gload_lds16(const void* g, void* l) {
    typedef const __attribute__((address_space(1))) unsigned int GU;
    typedef __attribute__((address_space(3))) unsigned int LU;
    __builtin_amdgcn_global_load_lds((GU*)(unsigned long long)g,
                                     (LU*)(unsigned long long)l, 16, 0, 0);
}

// ============ pack bodies: fp32 -> DMA-ready split-bf16 regions ============
__device__ __forceinline__ void pack_a_body(const float* __restrict__ X,
                                            ushortT* __restrict__ Ap,
                                            int M, int idx)
{
    int row = idx / 192, ch = idx - row * 192;
    int ks = ch >> 2, c = ch & 3;
    int mb = row >> 6, r = row & 63;
    ushx8 uh, ul;
    if (row < M) {
        const float* p = X + (size_t)row * DIM + (ch << 3);
        float4 a = *(const float4*)p;
        float4 b2 = *(const float4*)(p + 4);
        float xs[8] = {a.x, a.y, a.z, a.w, b2.x, b2.y, b2.z, b2.w};
        #pragma unroll
        for (int j = 0; j < 8; ++j) {
            ushortT hh = bf16r(xs[j]);
            union { unsigned u; float f; } w; w.u = ((unsigned)hh) << 16;
            uh[j] = hh; ul[j] = bf16r(xs[j] - w.f);
        }
    } else {
        #pragma unroll
        for (int j = 0; j < 8; ++j) { uh[j] = 0; ul[j] = 0; }
    }
    size_t base = (size_t)(mb * KSTEPS + ks) * AREG
                + r * 32 + ((c ^ ((r >> 1) & 3)) << 3);
    *(ushx8*)&Ap[base] = uh;
    *(ushx8*)&Ap[base + 2048] = ul;
}

__device__ __forceinline__ void pack_b_body(const float* __restrict__ W,
                                            ushortT* __restrict__ Bp, int idx)
{
    int row = idx / 192, ch = idx - row * 192;
    int ks = ch >> 2, c = ch & 3;
    int nb = row >> 7, rn = row & 127;
    const float* p = W + (size_t)row * DIM + (ch << 3);
    float4 a = *(const float4*)p;
    float4 b2 = *(const float4*)(p + 4);
    float xs[8] = {a.x, a.y, a.z, a.w, b2.x, b2.y, b2.z, b2.w};
    ushx8 uh, ul;
    #pragma unroll
    for (int j = 0; j < 8; ++j) {
        ushortT hh = bf16r(xs[j]);
        union { unsigned u; float f; } w; w.u = ((unsigned)hh) << 16;
        uh[j] = hh; ul[j] = bf16r(xs[j] - w.f);
    }
    size_t base = (size_t)(nb * KSTEPS + ks) * BREG
                + rn * 32 + ((c ^ ((rn >> 1) & 3)) << 3);
    *(ushx8*)&Bp[base] = uh;
    *(ushx8*)&Bp[base + 4096] = ul;
}

// pack1: x -> Ap, wq -> Bp0, wk -> Bp1 in one launch
__global__ __launch_bounds__(256)
void pack1_kernel(const float* __restrict__ x, const float* __restrict__ wq,
                  const float* __restrict__ wk,
                  ushortT* __restrict__ Ap, ushortT* __restrict__ Bp0,
                  ushortT* __restrict__ Bp1, int M, int gA, int gB)
{
    int b = blockIdx.x;
    if (b < gA) {
        pack_a_body(x, Ap, M, b * 256 + threadIdx.x);
    } else if (b < gA + gB) {
        pack_b_body(wq, Bp0, (b - gA) * 256 + threadIdx.x);
    } else {
        pack_b_body(wk, Bp1, (b - gA - gB) * 256 + threadIdx.x);
    }
}

// pack2: wv -> Bp0, wo -> Bp1 in one launch
__global__ __launch_bounds__(256)
void pack2_kernel(const float* __restrict__ wv, const float* __restrict__ wo,
                  ushortT* __restrict__ Bp0, ushortT* __restrict__ Bp1, int gB)
{
    int b = blockIdx.x;
    if (b < gB) pack_b_body(wv, Bp0, b * 256 + threadIdx.x);
    else        pack_b_body(wo, Bp1, (b - gB) * 256 + threadIdx.x);
}

// pack_a standalone (for o_buf after attn)
__global__ __launch_bounds__(256)
void pack_a_kernel(const float* __restrict__ X, ushortT* __restrict__ Ap,
                   int M, int Mpad)
{
    int idx = blockIdx.x * 256 + threadIdx.x;
    if (idx >= Mpad * 192) return;
    pack_a_body(X, Ap, M, idx);
}

// ============ fast split-bf16 GEMM body from packed A/B ============
// C = A(MxK) * B(NxK)^T + bias via Ah*Bh + Al*Bh + Ah*Bl. Tile 64x128, BK=32.
// DMA double-buffered staging, one barrier/kstep. 48 KB LDS -> 3 blocks/CU.
template<int MODE>   // 0: fp32 C + bias.  1: bf16 into swizzled tile-major vw
__device__ __forceinline__
void gemm_body(const ushortT* __restrict__ Ap, const ushortT* __restrict__ Bp,
               const float* __restrict__ bias, float* __restrict__ C,
               ushortT* __restrict__ vwout, int M, int nmb, int orig,
               const int* __restrict__ p_cs, const int* __restrict__ p_ge,
               const int* __restrict__ p_le,
               ushortT (*As)[AREG], ushortT (*Bs)[BREG])
{
    const int tid = threadIdx.x;
    const int wid = tid >> 6, lane = tid & 63;
    const int lo = lane & 15, hi = lane >> 4;
    const int wm = wid >> 1, wn = wid & 1;

    // bijective XCD swizzle, nb-major (orig&7 is XCD up to a constant rotation)
    const int nwg = nmb * (DIM / 128);
    const int xcd = orig & 7, linb = orig >> 3;
    const int qd = nwg >> 3, rr2 = nwg & 7;
    const int wg = (xcd < rr2 ? xcd * (qd + 1) : rr2 * (qd + 1) + (xcd - rr2) * qd) + linb;
    const int nb = wg / nmb, mb = wg - nb * nmb;
    const int m0 = mb << 6, n0 = nb << 7;

    f32x4 acc[2][4];
    #pragma unroll
    for (int i = 0; i < 2; ++i)
        #pragma unroll
        for (int j = 0; j < 4; ++j) acc[i][j] = (f32x4)(0.f);

    const ushortT* Asrc = Ap + (size_t)mb * (KSTEPS * AREG);
    const ushortT* Bsrc = Bp + (size_t)nb * (KSTEPS * BREG);
    const int lofs = lane << 3;
    const int aBase0 = (wid << 10) + lofs;
    const int aBase1 = aBase0 + 512;
    const int bBase  = (wid << 11) + lofs;

    gload_lds16(Asrc + aBase0, &As[0][aBase0]);
    gload_lds16(Asrc + aBase1, &As[0][aBase1]);
    #pragma unroll
    for (int i = 0; i < 4; ++i)
        gload_lds16(Bsrc + bBase + (i << 9), &Bs[0][bBase + (i << 9)]);

    const int cOff = ((hi ^ ((lo >> 1) & 3)) << 3);

    for (int ks = 0; ks < KSTEPS; ++ks) {
        const int b = ks & 1;
        __syncthreads();
        if (ks + 1 < KSTEPS) {
            const ushortT* as1 = Asrc + ((size_t)(ks + 1) << 12);
            const ushortT* bs1 = Bsrc + ((size_t)(ks + 1) << 13);
            gload_lds16(as1 + aBase0, &As[b ^ 1][aBase0]);
            gload_lds16(as1 + aBase1, &As[b ^ 1][aBase1]);
            #pragma unroll
            for (int i = 0; i < 4; ++i)
                gload_lds16(bs1 + bBase + (i << 9), &Bs[b ^ 1][bBase + (i << 9)]);
        }

        bf16x8 aH[2], aL[2];
        #pragma unroll
        for (int mf = 0; mf < 2; ++mf) {
            int r = (wm << 5) + (mf << 4) + lo;
            aH[mf] = *(const bf16x8*)&As[b][r * 32 + cOff];
            aL[mf] = *(const bf16x8*)&As[b][r * 32 + cOff + 2048];
        }
        #pragma unroll
        for (int nf = 0; nf < 4; ++nf) {
            int rn = (wn << 6) + (nf << 4) + lo;
            bf16x8 bH = *(const bf16x8*)&Bs[b][rn * 32 + cOff];
            bf16x8 bL = *(const bf16x8*)&Bs[b][rn * 32 + cOff + 4096];
            #pragma unroll
            for (int mf = 0; mf < 2; ++mf) {
                acc[mf][nf] = __builtin_amdgcn_mfma_f32_16x16x32_bf16(aH[mf], bH, acc[mf][nf], 0, 0, 0);
                acc[mf][nf] = __builtin_amdgcn_mfma_f32_16x16x32_bf16(aL[mf], bH, acc[mf][nf], 0, 0, 0);
                acc[mf][nf] = __builtin_amdgcn_mfma_f32_16x16x32_bf16(aH[mf], bL, acc[mf][nf], 0, 0, 0);
            }
        }
    }

    if (MODE == 0) {
        #pragma unroll
        for (int mf = 0; mf < 2; ++mf) {
            #pragma unroll
            for (int reg = 0; reg < 4; ++reg) {
                int gm = m0 + (wm << 5) + (mf << 4) + (hi << 2) + reg;
                if (gm < M) {
                    #pragma unroll
                    for (int nf = 0; nf < 4; ++nf) {
                        int gn = n0 + (wn << 6) + (nf << 4) + lo;
                        C[(size_t)gm * DIM + gn] = acc[mf][nf][reg] + bias[gn];
                    }
                }
            }
        }
    } else {
        const int S = M;
        const int local_end = p_le[0] + (p_cs[0] + S) - p_ge[0];
        int win_start = local_end - MAX_ATTN_WIN; if (win_start < 0) win_start = 0;
        const int vbase = (local_end - S) - win_start;
        #pragma unroll
        for (int mf = 0; mf < 2; ++mf) {
            #pragma unroll
            for (int reg = 0; reg < 4; ++reg) {
                int gm = m0 + (wm << 5) + (mf << 4) + (hi << 2) + reg;
                if (gm < M) {
                    #pragma unroll
                    for (int nf = 0; nf < 4; ++nf) {
                        int gn = n0 + (wn << 6) + (nf << 4) + lo;
                        int h2 = gn >> 7, d = gn & 127;
                        int pos = vbase + gm;
                        int tt = pos >> 6, w = pos & 63;
                        int swz = (((w >> 3) ^ (d & 7)) << 3) | (w & 7);
                        vwout[((size_t)h2 * NT_MAX + tt) * TILE_ELEMS + ((size_t)d << 6) + swz] =
                            bf16r(acc[mf][nf][reg] + bias[gn]);
                    }
                }
            }
        }
    }
}

// fused Q+K projection: blocks [0,nwg) -> Q, [nwg,2nwg) -> K (shared A panel in L2)
__global__ __launch_bounds__(256, 3)
void gemm_qk_kernel(const ushortT* __restrict__ Ap,
                    const ushortT* __restrict__ BpQ, const ushortT* __restrict__ BpK,
                    const float* __restrict__ bq, const float* __restrict__ bk,
                    float* __restrict__ Cq, float* __restrict__ Ck,
                    int M, int nmb, int nwg)
{
    __shared__ __align__(16) ushortT As[2][AREG];
    __shared__ __align__(16) ushortT Bs[2][BREG];
    int gid = (int)blockIdx.x;
    if (gid < nwg)
        gemm_body<0>(Ap, BpQ, bq, Cq, nullptr, M, nmb, gid, nullptr, nullptr, nullptr, As, Bs);
    else
        gemm_body<0>(Ap, BpK, bk, Ck, nullptr, M, nmb, gid - nwg, nullptr, nullptr, nullptr, As, Bs);
}

template<int MODE>
__global__ __launch_bounds__(256, 3)
void gemm_single_kernel(const ushortT* __restrict__ Ap, const ushortT* __restrict__ Bp,
                        const float* __restrict__ bias, float* __restrict__ C,
                        ushortT* __restrict__ vwout, int M, int nmb,
                        const int* __restrict__ p_cs, const int* __restrict__ p_ge,
                        const int* __restrict__ p_le)
{
    __shared__ __align__(16) ushortT As[2][AREG];
    __shared__ __align__(16) ushortT Bs[2][BREG];
    gemm_body<MODE>(Ap, Bp, bias, C, vwout, M, nmb, (int)blockIdx.x,
                    p_cs, p_ge, p_le, As, Bs);
}

// ============ fused RMSNorm + RoPE (in-place, one block per token) ============
__global__ __launch_bounds__(256)
void rmsnorm_rope_kernel(float* __restrict__ qbuf, float* __restrict__ kbuf,
                         const float* __restrict__ gq, const float* __restrict__ gk,
                         const float* __restrict__ theta,
                         const int* __restrict__ p_gh, const int* __restrict__ p_gw,
                         const int* __restrict__ p_cs, int S)
{
    const int s = blockIdx.x;
    float* row = ((blockIdx.y == 0) ? qbuf : kbuf) + (size_t)s * DIM;
    const float* g = (blockIdx.y == 0) ? gq : gk;
    const int tid = threadIdx.x;

    float v[6];
    #pragma unroll
    for (int i = 0; i < 6; ++i) v[i] = row[tid * 6 + i];
    float ss = 0.f;
    #pragma unroll
    for (int i = 0; i < 6; ++i) ss += v[i] * v[i];
    #pragma unroll
    for (int off = 32; off > 0; off >>= 1) ss += __shfl_xor(ss, off, 64);

    __shared__ float red[4];
    if ((tid & 63) == 0) red[tid >> 6] = ss;
    __syncthreads();
    float tot = red[0] + red[1] + red[2] + red[3];
    float rs = rsqrtf(tot * (1.0f / DIM) + RMS_EPS);

    const int H = p_gh[0], W = p_gw[0];
    const int fs = p_cs[0] / (H * W);
    const int fr = s / (H * W);
    const int rem = s - fr * (H * W);
    const int hh = rem / W;
    const int ww = rem - hh * W;

    #pragma unroll
    for (int pi = 0; pi < 3; ++pi) {
        int p = tid * 3 + pi;
        int j = p & 63;
        float xr = v[pi * 2]     * rs * g[tid * 6 + pi * 2];
        float xi = v[pi * 2 + 1] * rs * g[tid * 6 + pi * 2 + 1];
        int rowi = (j < 22) ? (fs + fr) : ((j < 43) ? hh : ww);
        float ang = theta[rowi * 64 + j];
        float sn, cs;
        sincosf(ang, &sn, &cs);
        row[tid * 6 + pi * 2]     = xr * cs - xi * sn;
        row[tid * 6 + pi * 2 + 1] = xr * sn + xi * cs;
    }
}

// ============ fused K window + cached-V pack ============
// y = [0,12): pack K head y.  y = [12,24): pack cached V head y-12.
__global__ __launch_bounds__(256)
void pack_kv_kernel(const float* __restrict__ cache_k, const float* __restrict__ k_lin,
                    const float* __restrict__ cache_v,
                    ushortT* __restrict__ kw, ushortT* __restrict__ vw,
                    const int* __restrict__ p_cs, const int* __restrict__ p_ge,
                    const int* __restrict__ p_le, int S)
{
    const int kt = blockIdx.x;
    const int local_end = p_le[0] + (p_cs[0] + S) - p_ge[0];
    int win_start = local_end - MAX_ATTN_WIN; if (win_start < 0) win_start = 0;
    const int L = local_end - win_start;
    const int cpart = (local_end - S) - win_start;

    if (blockIdx.y < NHEADS) {
        const int h = blockIdx.y;
        #pragma unroll
        for (int i = 0; i < 4; ++i) {
            int cid = (i << 8) + threadIdx.x;
            int r = cid >> 4, c = cid & 15;
            int pos = (kt << 6) + r;
            ushx8 u;
            if (pos < L) {
                const float* src = (pos < cpart)
                    ? &cache_k[(size_t)(win_start + pos) * DIM + h * HD + (c << 3)]
                    : &k_lin[(size_t)(pos - cpart) * DIM + h * HD + (c << 3)];
                float4 a = *(const float4*)src;
                float4 b = *(const float4*)(src + 4);
                u = pack8(a, b);
            } else {
                #pragma unroll
                for (int j = 0; j < 8; ++j) u[j] = 0;
            }
            *(ushx8*)&kw[(size_t)h * (KWROWS * HD) + (size_t)pos * HD + ((c ^ (r & 15)) << 3)] = u;
        }
    } else {
        const int h = blockIdx.y - NHEADS;
        const int tbase = kt << 6;
        if (tbase >= cpart && tbase + 64 <= L) return;   // fully gemm<1>-written

        __shared__ float tile[64 * 132];
        #pragma unroll
        for (int i = 0; i < 8; ++i) {
            int cid = (i << 8) + threadIdx.x;
            int r = cid >> 5, fc = cid & 31;
            int pos = tbase + r;
            float4 vv = (pos < cpart)
                ? *(const float4*)&cache_v[(size_t)(win_start + pos) * DIM + h * HD + (fc << 2)]
                : make_float4(0.f, 0.f, 0.f, 0.f);
            *(float4*)&tile[r * 132 + (fc << 2)] = vv;
        }
        __syncthreads();
        #pragma unroll
        for (int i = 0; i < 4; ++i) {
            int cid = (i << 8) + threadIdx.x;
            int d = cid >> 3, kc = cid & 7;
            int kglob = tbase + (kc << 3);
            ushx8 u;
            #pragma unroll
            for (int j = 0; j < 8; ++j)
                u[j] = bf16r(tile[((kc << 3) + j) * 132 + d]);
            size_t base = ((size_t)h * NT_MAX + kt) * TILE_ELEMS + ((size_t)d << 6)
                        + ((size_t)((kc ^ (d & 7)) << 3));
            if (kglob + 8 <= cpart) {
                *(ushx8*)&vw[base] = u;
            } else {
                #pragma unroll
                for (int j = 0; j < 8; ++j) {
                    int pos = kglob + j;
                    if (pos < cpart)      vw[base + j] = u[j];
                    else if (pos >= L)    vw[base + j] = 0;
                }
            }
        }
    }
}

// ============ MFMA flash attention v7: 2-wave blocks, 32 q-rows/wave ============
// v6's per-q-halved LDS traffic (each bF/vF read feeds 2 MFMAs) + v5's grid:
// QBLK=64 via 128-thread blocks -> 588 blocks, 48 KB LDS -> 3 blocks/CU.
// K single-buffered + mid-tile restage, V double-buffered, DMA staging.
// Each wave owns HALF of Ks (4096 ush) as DMA dest; P round-trip (2048 ush)
// aliases the first half of that region (same-wave ordered via lgkmcnt(0)).
__global__ __launch_bounds__(128, 2)
void attn_mfma7_kernel(const float* __restrict__ q_lin,
                       const ushortT* __restrict__ kw, const ushortT* __restrict__ vw,
                       float* __restrict__ obuf,
                       const int* __restrict__ p_cs, const int* __restrict__ p_ge,
                       const int* __restrict__ p_le, int S, int nqb)
{
    __shared__ __align__(16) ushortT Ks[TILE_ELEMS];      // 16 KB single
    __shared__ __align__(16) ushortT Vs[2][TILE_ELEMS];   // 32 KB double

    const int tid = threadIdx.x;
    const int wid = tid >> 6, lane = tid & 63;
    const int lo = lane & 15, hi = lane >> 4;

    const int nwg = nqb * NHEADS;
    const int orig = (int)blockIdx.x;
    const int xcd = orig & 7, linb = orig >> 3;
    const int qd = nwg >> 3, rr = nwg & 7;
    const int wg = (xcd < rr ? xcd * (qd + 1) : rr * (qd + 1) + (xcd - rr) * qd) + linb;
    const int h = wg / nqb;
    const int q0 = (wg - h * nqb) << 6;

    const int local_end = p_le[0] + (p_cs[0] + S) - p_ge[0];
    int win_start = local_end - MAX_ATTN_WIN; if (win_start < 0) win_start = 0;
    const int L = local_end - win_start;
    const int ntiles = (L + 63) >> 6;

    // Q A-frags: 2 subtiles of 16 rows; wave covers q rows [q0+wid*32, +32)
    bf16x8 aQ[2][4];
    #pragma unroll
    for (int sub = 0; sub < 2; ++sub) {
        int q = q0 + (wid << 5) + (sub << 4) + lo;
        if (q < S) {
            const float* qp = q_lin + (size_t)q * DIM + h * HD + (hi << 3);
            #pragma unroll
            for (int ks = 0; ks < 4; ++ks) {
                float4 a = *(const float4*)&qp[ks * 32];
                float4 b = *(const float4*)&qp[ks * 32 + 4];
                ushx8 u = pack8(a, b);
                aQ[sub][ks] = *(bf16x8*)&u;
            }
        } else {
            ushx8 z;
            #pragma unroll
            for (int j = 0; j < 8; ++j) z[j] = 0;
            #pragma unroll
            for (int ks = 0; ks < 4; ++ks) aQ[sub][ks] = *(bf16x8*)&z;
        }
    }

    f32x4 Oa[2][8];
    float lsum[2][4];
    #pragma unroll
    for (int sub = 0; sub < 2; ++sub) {
        #pragma unroll
        for (int i = 0; i < 8; ++i) Oa[sub][i] = (f32x4)(0.f);
        #pragma unroll
        for (int i = 0; i < 4; ++i) lsum[sub][i] = 0.f;
    }

    const ushortT* kwp = kw + (size_t)h * (NT_MAX * TILE_ELEMS);
    const ushortT* vwp = vw + (size_t)h * (NT_MAX * TILE_ELEMS);
    const float scale = 0.08838834764831845f;   // 1/sqrt(128)
    const int pbase = wid << 12;                // wave's half of Ks (4096 ush)
    const int sbase = (wid << 12) + (lane << 3);

    // prologue: stage K(0), V(0) — 8 chunks of 512 ush per wave each
    #pragma unroll
    for (int i = 0; i < 8; ++i) {
        gload_lds16(kwp + sbase + (i << 9), &Ks[sbase + (i << 9)]);
        gload_lds16(vwp + sbase + (i << 9), &Vs[0][sbase + (i << 9)]);
    }

    for (int t = 0; t < ntiles; ++t) {
        const int b = t & 1;
        __syncthreads();   // A: drains K(t),V(t) DMAs for all waves

        // ---- S = Q K^T, both subtiles share each bF read ----
        f32x4 Sa[2][4];
        #pragma unroll
        for (int nt = 0; nt < 4; ++nt) { Sa[0][nt] = (f32x4)(0.f); Sa[1][nt] = (f32x4)(0.f); }
        #pragma unroll
        for (int nt = 0; nt < 4; ++nt) {
            const int kr = (nt << 4) + lo;
            #pragma unroll
            for (int ks = 0; ks < 4; ++ks) {
                bf16x8 bF = *(const bf16x8*)&Ks[kr * 128 + ((((ks << 2) + hi) ^ (kr & 15)) << 3)];
                Sa[0][nt] = __builtin_amdgcn_mfma_f32_16x16x32_bf16(aQ[0][ks], bF, Sa[0][nt], 0, 0, 0);
                Sa[1][nt] = __builtin_amdgcn_mfma_f32_16x16x32_bf16(aQ[1][ks], bF, Sa[1][nt], 0, 0, 0);
            }
        }

        __syncthreads();   // B: all waves' Ks reads done (nothing in vmcnt flight)

        // issue V(t+1) -> other half (covered by softmax+P+PV, drained at next A)
        if (t + 1 < ntiles) {
            const ushortT* vsrc = vwp + ((size_t)(t + 1) << 13);
            ushortT* vdst = &Vs[b ^ 1][0];
            #pragma unroll
            for (int i = 0; i < 8; ++i)
                gload_lds16(vsrc + sbase + (i << 9), vdst + sbase + (i << 9));
        }

        // ---- fixed-max softmax: p = exp(s*scale - 20); accumulate l ----
        const bool tail = (((t + 1) << 6) > L);
        #pragma unroll
        for (int sub = 0; sub < 2; ++sub) {
            #pragma unroll
            for (int nt = 0; nt < 4; ++nt) {
                #pragma unroll
                for (int reg = 0; reg < 4; ++reg) {
                    float sv = Sa[sub][nt][reg] * scale - 20.f;
                    if (tail) {
                        int kg = (t << 6) + (nt << 4) + lo;
                        if (kg >= L) sv = -1e30f;
                    }
                    float p = __expf(sv);
                    lsum[sub][reg] += p;
                    Sa[sub][nt][reg] = p;
                }
            }
        }

        // ---- P round-trip via OWN Ks half (same-wave DS ordered) ----
        #pragma unroll
        for (int sub = 0; sub < 2; ++sub) {
            #pragma unroll
            for (int nt = 0; nt < 4; ++nt) {
                #pragma unroll
                for (int reg = 0; reg < 4; ++reg) {
                    int r = (hi << 2) + reg;
                    int cc = (nt << 1) + (lo >> 3);
                    Ks[pbase + (sub << 10) + (r << 6) + ((cc ^ (r & 7)) << 3) + (lo & 7)] =
                        bf16r(Sa[sub][nt][reg]);
                }
            }
        }
        bf16x8 pF[2][2];
        #pragma unroll
        for (int sub = 0; sub < 2; ++sub)
            #pragma unroll
            for (int ks = 0; ks < 2; ++ks)
                pF[sub][ks] = *(const bf16x8*)&Ks[pbase + (sub << 10) + (lo << 6)
                                                 + ((((ks << 2) + hi) ^ (lo & 7)) << 3)];

        // P data must be in registers before our K-DMA overwrites the region
        asm volatile("s_waitcnt lgkmcnt(0)" ::: "memory");
        __builtin_amdgcn_sched_barrier(0);

        // issue K(t+1) into own half (covered by PV, drained at next A)
        if (t + 1 < ntiles) {
            const ushortT* ksrc = kwp + ((size_t)(t + 1) << 13);
            #pragma unroll
            for (int i = 0; i < 8; ++i)
                gload_lds16(ksrc + sbase + (i << 9), &Ks[sbase + (i << 9)]);
        }

        // ---- O += P V, both subtiles share each vF read ----
        #pragma unroll
        for (int nto = 0; nto < 8; ++nto) {
            const int d = (nto << 4) + lo;
            #pragma unroll
            for (int ks = 0; ks < 2; ++ks) {
                bf16x8 vF = *(const bf16x8*)&Vs[b][(d << 6) + ((((ks << 2) + hi) ^ (d & 7)) << 3)];
                Oa[0][nto] = __builtin_amdgcn_mfma_f32_16x16x32_bf16(pF[0][ks], vF, Oa[0][nto], 0, 0, 0);
                Oa[1][nto] = __builtin_amdgcn_mfma_f32_16x16x32_bf16(pF[1][ks], vF, Oa[1][nto], 0, 0, 0);
            }
        }
    }

    #pragma unroll
    for (int sub = 0; sub < 2; ++sub) {
        #pragma unroll
        for (int reg = 0; reg < 4; ++reg) {
            #pragma unroll
            for (int off = 1; off < 16; off <<= 1)
                lsum[sub][reg] += __shfl_xor(lsum[sub][reg], off, 64);
        }
        #pragma unroll
        for (int reg = 0; reg < 4; ++reg) {
            int q = q0 + (wid << 5) + (sub << 4) + (hi << 2) + reg;
            if (q < S) {
                float inv = 1.f / lsum[sub][reg];
                #pragma unroll
                for (int nto = 0; nto < 8; ++nto)
                    obuf[(size_t)q * DIM + h * HD + (nto << 4) + lo] = Oa[sub][nto][reg] * inv;
            }
        }
    }
}

// ==================== launch ====================
extern "C" void kernel_launch(void* const* d_in, const int* in_sizes, int n_in,
                              void* d_out, int out_size, void* d_ws, size_t ws_size,
                              hipStream_t stream)
{
    const float* x       = (const float*)d_in[0];
    const float* theta   = (const float*)d_in[1];
    const float* cache_k = (const float*)d_in[2];
    const float* cache_v = (const float*)d_in[3];
    const float* wq = (const float*)d_in[4];
    const float* bq = (const float*)d_in[5];
    const float* wk = (const float*)d_in[6];
    const float* bk = (const float*)d_in[7];
    const float* wv = (const float*)d_in[8];
    const float* bv = (const float*)d_in[9];
    const float* wo = (const float*)d_in[10];
    const float* bo = (const float*)d_in[11];
    const float* gq = (const float*)d_in[12];
    const float* gk = (const float*)d_in[13];
    const int* p_gh = (const int*)d_in[15];
    const int* p_gw = (const int*)d_in[16];
    const int* p_cs = (const int*)d_in[17];
    const int* p_ge = (const int*)d_in[18];
    const int* p_le = (const int*)d_in[19];

    const int S = in_sizes[0] / DIM;
    const int nmb = (S + 63) / 64;                   // 49
    const int Mpad = nmb * 64;

    float* q_lin = (float*)d_ws;
    float* k_lin = q_lin + (size_t)S * DIM;
    float* o_buf = k_lin;
    ushortT* Ap  = (ushortT*)(k_lin + (size_t)S * DIM);
    ushortT* kw  = Ap;                                 // alias (Ap dead when kw written)
    ushortT* vw  = Ap + (size_t)nmb * KSTEPS * AREG;
    ushortT* Bp0 = vw + (size_t)NHEADS * NT_MAX * TILE_ELEMS;
    ushortT* Bp1 = Bp0 + (size_t)NHEADS * KSTEPS * BREG;

    dim3 blk(256);
    const int nwgG = nmb * (DIM / 128);                // 588
    const int gA = (Mpad * 192) / 256;                 // 2352
    const int gB = (DIM * 192) / 256;                  // 1152

    pack1_kernel<<<gA + 2 * gB, blk, 0, stream>>>(x, wq, wk, Ap, Bp0, Bp1, S, gA, gB);
    gemm_qk_kernel<<<2 * nwgG, blk, 0, stream>>>(Ap, Bp0, Bp1, bq, bk,
                                                 q_lin, k_lin, S, nmb, nwgG);
    pack2_kernel<<<2 * gB, blk, 0, stream>>>(wv, wo, Bp0, Bp1, gB);
    gemm_single_kernel<1><<<nwgG, blk, 0, stream>>>(Ap, Bp0, bv, nullptr, vw,
                                                    S, nmb, p_cs, p_ge, p_le);

    rmsnorm_rope_kernel<<<dim3(S, 2), blk, 0, stream>>>(q_lin, k_lin, gq, gk, theta,
                                                        p_gh, p_gw, p_cs, S);

    pack_kv_kernel<<<dim3(NT_MAX, 2 * NHEADS), blk, 0, stream>>>(
        cache_k, k_lin, cache_v, kw, vw, p_cs, p_ge, p_le, S);

    const int nqb = (S + 63) / 64;                     // 49 -> 588 blocks
    attn_mfma7_kernel<<<dim3(nqb * NHEADS), dim3(128), 0, stream>>>(
        q_lin, kw, vw, o_buf, p_cs, p_ge, p_le, S, nqb);

    pack_a_kernel<<<gA, blk, 0, stream>>>(o_buf, Ap, S, Mpad);
    gemm_single_kernel<0><<<nwgG, blk, 0, stream>>>(Ap, Bp1, bo, (float*)d_out, nullptr,
                                                    S, nmb, p_cs, p_ge, p_le);
}

// Round 7
// 656.668 us; speedup vs baseline: 1.0852x; 1.0229x over previous
//
#include <hip/hip_runtime.h>

#define DIM 1536
#define NHEADS 12
#define HD 128
#define MAX_ATTN_WIN 5632
#define RMS_EPS 1e-6f
#define KWROWS 5632
#define NT_MAX 88            // KWROWS / 64
#define TILE_ELEMS 8192      // 64 * 128 ushorts per K/V tile
#define KSTEPS 48            // DIM / 32
#define AREG 4096            // ushorts per A region (64 x 32 x {hi,lo})
#define BREG 8192            // ushorts per B region (128 x 32 x {hi,lo})

typedef unsigned short ushortT;
typedef __bf16 bf16x8 __attribute__((ext_vector_type(8)));
typedef float f32x4 __attribute__((ext_vector_type(4)));
typedef ushortT ushx8 __attribute__((ext_vector_type(8)));

__device__ __forceinline__ ushortT bf16r(float x) {
    union { float f; unsigned u; } v; v.f = x;
    unsigned r = v.u + 0x7FFFu + ((v.u >> 16) & 1u);
    return (ushortT)(r >> 16);
}
__device__ __forceinline__ ushx8 pack8(float4 a, float4 b) {
    ushx8 u;
    u[0] = bf16r(a.x); u[1] = bf16r(a.y); u[2] = bf16r(a.z); u[3] = bf16r(a.w);
    u[4] = bf16r(b.x); u[5] = bf16r(b.y); u[6] = bf16r(b.z); u[7] = bf16r(b.w);
    return u;
}

// async global->LDS, 16B per lane. LDS dest must be wave-uniform base + lane*16.
__device__ __forceinline__ void gload_lds16(const void* g, void* l) {
    typedef const __attribute__((address_space(1))) unsigned int GU;
    typedef __attribute__((address_space(3))) unsigned int LU;
    __builtin_amdgcn_global_load_lds((GU*)(unsigned long long)g,
                                     (LU*)(unsigned long long)l, 16, 0, 0);
}

// ============ pack bodies: fp32 -> DMA-ready split-bf16 regions ============
__device__ __forceinline__ void pack_a_body(const float* __restrict__ X,
                                            ushortT* __restrict__ Ap,
                                            int M, int idx)
{
    int row = idx / 192, ch = idx - row * 192;
    int ks = ch >> 2, c = ch & 3;
    int mb = row >> 6, r = row & 63;
    ushx8 uh, ul;
    if (row < M) {
        const float* p = X + (size_t)row * DIM + (ch << 3);
        float4 a = *(const float4*)p;
        float4 b2 = *(const float4*)(p + 4);
        float xs[8] = {a.x, a.y, a.z, a.w, b2.x, b2.y, b2.z, b2.w};
        #pragma unroll
        for (int j = 0; j < 8; ++j) {
            ushortT hh = bf16r(xs[j]);
            union { unsigned u; float f; } w; w.u = ((unsigned)hh) << 16;
            uh[j] = hh; ul[j] = bf16r(xs[j] - w.f);
        }
    } else {
        #pragma unroll
        for (int j = 0; j < 8; ++j) { uh[j] = 0; ul[j] = 0; }
    }
    size_t base = (size_t)(mb * KSTEPS + ks) * AREG
                + r * 32 + ((c ^ ((r >> 1) & 3)) << 3);
    *(ushx8*)&Ap[base] = uh;
    *(ushx8*)&Ap[base + 2048] = ul;
}

__device__ __forceinline__ void pack_b_body(const float* __restrict__ W,
                                            ushortT* __restrict__ Bp, int idx)
{
    int row = idx / 192, ch = idx - row * 192;
    int ks = ch >> 2, c = ch & 3;
    int nb = row >> 7, rn = row & 127;
    const float* p = W + (size_t)row * DIM + (ch << 3);
    float4 a = *(const float4*)p;
    float4 b2 = *(const float4*)(p + 4);
    float xs[8] = {a.x, a.y, a.z, a.w, b2.x, b2.y, b2.z, b2.w};
    ushx8 uh, ul;
    #pragma unroll
    for (int j = 0; j < 8; ++j) {
        ushortT hh = bf16r(xs[j]);
        union { unsigned u; float f; } w; w.u = ((unsigned)hh) << 16;
        uh[j] = hh; ul[j] = bf16r(xs[j] - w.f);
    }
    size_t base = (size_t)(nb * KSTEPS + ks) * BREG
                + rn * 32 + ((c ^ ((rn >> 1) & 3)) << 3);
    *(ushx8*)&Bp[base] = uh;
    *(ushx8*)&Bp[base + 4096] = ul;
}

// pack_all: x -> Ap, wq -> Bp0, wk -> Bp1, wv -> Bp2 in one launch
__global__ __launch_bounds__(256)
void pack_all_kernel(const float* __restrict__ x, const float* __restrict__ wq,
                     const float* __restrict__ wk, const float* __restrict__ wv,
                     ushortT* __restrict__ Ap, ushortT* __restrict__ Bp0,
                     ushortT* __restrict__ Bp1, ushortT* __restrict__ Bp2,
                     int M, int gA, int gB)
{
    int b = blockIdx.x;
    if (b < gA) { pack_a_body(x, Ap, M, b * 256 + threadIdx.x); return; }
    b -= gA;
    if (b < gB)            pack_b_body(wq, Bp0, b * 256 + threadIdx.x);
    else if (b < 2 * gB)   pack_b_body(wk, Bp1, (b - gB) * 256 + threadIdx.x);
    else                   pack_b_body(wv, Bp2, (b - 2 * gB) * 256 + threadIdx.x);
}

// pack_a standalone (for o_buf after attn)
__global__ __launch_bounds__(256)
void pack_a_kernel(const float* __restrict__ X, ushortT* __restrict__ Ap,
                   int M, int Mpad)
{
    int idx = blockIdx.x * 256 + threadIdx.x;
    if (idx >= Mpad * 192) return;
    pack_a_body(X, Ap, M, idx);
}

// ============ fast split-bf16 GEMM body from packed A/B ============
template<int MODE>   // 0: fp32 C + bias.  1: bf16 into swizzled tile-major vw
__device__ __forceinline__
void gemm_body(const ushortT* __restrict__ Ap, const ushortT* __restrict__ Bp,
               const float* __restrict__ bias, float* __restrict__ C,
               ushortT* __restrict__ vwout, int M, int nmb, int orig,
               const int* __restrict__ p_cs, const int* __restrict__ p_ge,
               const int* __restrict__ p_le,
               ushortT (*As)[AREG], ushortT (*Bs)[BREG])
{
    const int tid = threadIdx.x;
    const int wid = tid >> 6, lane = tid & 63;
    const int lo = lane & 15, hi = lane >> 4;
    const int wm = wid >> 1, wn = wid & 1;

    const int nwg = nmb * (DIM / 128);
    const int xcd = orig & 7, linb = orig >> 3;
    const int qd = nwg >> 3, rr2 = nwg & 7;
    const int wg = (xcd < rr2 ? xcd * (qd + 1) : rr2 * (qd + 1) + (xcd - rr2) * qd) + linb;
    const int nb = wg / nmb, mb = wg - nb * nmb;
    const int m0 = mb << 6, n0 = nb << 7;

    f32x4 acc[2][4];
    #pragma unroll
    for (int i = 0; i < 2; ++i)
        #pragma unroll
        for (int j = 0; j < 4; ++j) acc[i][j] = (f32x4)(0.f);

    const ushortT* Asrc = Ap + (size_t)mb * (KSTEPS * AREG);
    const ushortT* Bsrc = Bp + (size_t)nb * (KSTEPS * BREG);
    const int lofs = lane << 3;
    const int aBase0 = (wid << 10) + lofs;
    const int aBase1 = aBase0 + 512;
    const int bBase  = (wid << 11) + lofs;

    gload_lds16(Asrc + aBase0, &As[0][aBase0]);
    gload_lds16(Asrc + aBase1, &As[0][aBase1]);
    #pragma unroll
    for (int i = 0; i < 4; ++i)
        gload_lds16(Bsrc + bBase + (i << 9), &Bs[0][bBase + (i << 9)]);

    const int cOff = ((hi ^ ((lo >> 1) & 3)) << 3);

    for (int ks = 0; ks < KSTEPS; ++ks) {
        const int b = ks & 1;
        __syncthreads();
        if (ks + 1 < KSTEPS) {
            const ushortT* as1 = Asrc + ((size_t)(ks + 1) << 12);
            const ushortT* bs1 = Bsrc + ((size_t)(ks + 1) << 13);
            gload_lds16(as1 + aBase0, &As[b ^ 1][aBase0]);
            gload_lds16(as1 + aBase1, &As[b ^ 1][aBase1]);
            #pragma unroll
            for (int i = 0; i < 4; ++i)
                gload_lds16(bs1 + bBase + (i << 9), &Bs[b ^ 1][bBase + (i << 9)]);
        }

        bf16x8 aH[2], aL[2];
        #pragma unroll
        for (int mf = 0; mf < 2; ++mf) {
            int r = (wm << 5) + (mf << 4) + lo;
            aH[mf] = *(const bf16x8*)&As[b][r * 32 + cOff];
            aL[mf] = *(const bf16x8*)&As[b][r * 32 + cOff + 2048];
        }
        #pragma unroll
        for (int nf = 0; nf < 4; ++nf) {
            int rn = (wn << 6) + (nf << 4) + lo;
            bf16x8 bH = *(const bf16x8*)&Bs[b][rn * 32 + cOff];
            bf16x8 bL = *(const bf16x8*)&Bs[b][rn * 32 + cOff + 4096];
            #pragma unroll
            for (int mf = 0; mf < 2; ++mf) {
                acc[mf][nf] = __builtin_amdgcn_mfma_f32_16x16x32_bf16(aH[mf], bH, acc[mf][nf], 0, 0, 0);
                acc[mf][nf] = __builtin_amdgcn_mfma_f32_16x16x32_bf16(aL[mf], bH, acc[mf][nf], 0, 0, 0);
                acc[mf][nf] = __builtin_amdgcn_mfma_f32_16x16x32_bf16(aH[mf], bL, acc[mf][nf], 0, 0, 0);
            }
        }
    }

    if (MODE == 0) {
        #pragma unroll
        for (int mf = 0; mf < 2; ++mf) {
            #pragma unroll
            for (int reg = 0; reg < 4; ++reg) {
                int gm = m0 + (wm << 5) + (mf << 4) + (hi << 2) + reg;
                if (gm < M) {
                    #pragma unroll
                    for (int nf = 0; nf < 4; ++nf) {
                        int gn = n0 + (wn << 6) + (nf << 4) + lo;
                        C[(size_t)gm * DIM + gn] = acc[mf][nf][reg] + bias[gn];
                    }
                }
            }
        }
    } else {
        const int S = M;
        const int local_end = p_le[0] + (p_cs[0] + S) - p_ge[0];
        int win_start = local_end - MAX_ATTN_WIN; if (win_start < 0) win_start = 0;
        const int vbase = (local_end - S) - win_start;
        #pragma unroll
        for (int mf = 0; mf < 2; ++mf) {
            #pragma unroll
            for (int reg = 0; reg < 4; ++reg) {
                int gm = m0 + (wm << 5) + (mf << 4) + (hi << 2) + reg;
                if (gm < M) {
                    #pragma unroll
                    for (int nf = 0; nf < 4; ++nf) {
                        int gn = n0 + (wn << 6) + (nf << 4) + lo;
                        int h2 = gn >> 7, d = gn & 127;
                        int pos = vbase + gm;
                        int tt = pos >> 6, w = pos & 63;
                        int swz = (((w >> 3) ^ (d & 7)) << 3) | (w & 7);
                        vwout[((size_t)h2 * NT_MAX + tt) * TILE_ELEMS + ((size_t)d << 6) + swz] =
                            bf16r(acc[mf][nf][reg] + bias[gn]);
                    }
                }
            }
        }
    }
}

// fused Q+K+V projection: [0,nwg) Q, [nwg,2nwg) K, [2nwg,3nwg) V (shared A panel)
__global__ __launch_bounds__(256, 3)
void gemm_qkv_kernel(const ushortT* __restrict__ Ap,
                     const ushortT* __restrict__ BpQ, const ushortT* __restrict__ BpK,
                     const ushortT* __restrict__ BpV,
                     const float* __restrict__ bq, const float* __restrict__ bk,
                     const float* __restrict__ bv,
                     float* __restrict__ Cq, float* __restrict__ Ck,
                     ushortT* __restrict__ vw,
                     int M, int nmb, int nwg,
                     const int* __restrict__ p_cs, const int* __restrict__ p_ge,
                     const int* __restrict__ p_le)
{
    __shared__ __align__(16) ushortT As[2][AREG];
    __shared__ __align__(16) ushortT Bs[2][BREG];
    int gid = (int)blockIdx.x;
    if (gid < nwg)
        gemm_body<0>(Ap, BpQ, bq, Cq, nullptr, M, nmb, gid, nullptr, nullptr, nullptr, As, Bs);
    else if (gid < 2 * nwg)
        gemm_body<0>(Ap, BpK, bk, Ck, nullptr, M, nmb, gid - nwg, nullptr, nullptr, nullptr, As, Bs);
    else
        gemm_body<1>(Ap, BpV, bv, nullptr, vw, M, nmb, gid - 2 * nwg, p_cs, p_ge, p_le, As, Bs);
}

template<int MODE>
__global__ __launch_bounds__(256, 3)
void gemm_single_kernel(const ushortT* __restrict__ Ap, const ushortT* __restrict__ Bp,
                        const float* __restrict__ bias, float* __restrict__ C,
                        ushortT* __restrict__ vwout, int M, int nmb,
                        const int* __restrict__ p_cs, const int* __restrict__ p_ge,
                        const int* __restrict__ p_le)
{
    __shared__ __align__(16) ushortT As[2][AREG];
    __shared__ __align__(16) ushortT Bs[2][BREG];
    gemm_body<MODE>(Ap, Bp, bias, C, vwout, M, nmb, (int)blockIdx.x,
                    p_cs, p_ge, p_le, As, Bs);
}

// ============ fused RMSNorm + RoPE; K path writes bf16-swizzled kw directly ====
// y=0: q row -> norm+rope -> q_lin (fp32, in place).
// y=1: k row -> norm+rope -> kw[h][pos][swz] (bf16), pos = cpart + s.
//      Saves k_lin write-back + pack re-read.
__global__ __launch_bounds__(256)
void rmsnorm_rope_kernel(float* __restrict__ qbuf, float* __restrict__ kbuf,
                         ushortT* __restrict__ kw,
                         const float* __restrict__ gq, const float* __restrict__ gk,
                         const float* __restrict__ theta,
                         const int* __restrict__ p_gh, const int* __restrict__ p_gw,
                         const int* __restrict__ p_cs, const int* __restrict__ p_ge,
                         const int* __restrict__ p_le, int S)
{
    const int s = blockIdx.x;
    const bool isQ = (blockIdx.y == 0);
    float* row = (isQ ? qbuf : kbuf) + (size_t)s * DIM;
    const float* g = isQ ? gq : gk;
    const int tid = threadIdx.x;

    float v[6];
    #pragma unroll
    for (int i = 0; i < 6; ++i) v[i] = row[tid * 6 + i];
    float ss = 0.f;
    #pragma unroll
    for (int i = 0; i < 6; ++i) ss += v[i] * v[i];
    #pragma unroll
    for (int off = 32; off > 0; off >>= 1) ss += __shfl_xor(ss, off, 64);

    __shared__ float red[4];
    __shared__ ushortT krow[DIM];
    if ((tid & 63) == 0) red[tid >> 6] = ss;
    __syncthreads();
    float tot = red[0] + red[1] + red[2] + red[3];
    float rs = rsqrtf(tot * (1.0f / DIM) + RMS_EPS);

    const int H = p_gh[0], W = p_gw[0];
    const int fs = p_cs[0] / (H * W);
    const int fr = s / (H * W);
    const int rem = s - fr * (H * W);
    const int hh = rem / W;
    const int ww = rem - hh * W;

    float out[6];
    #pragma unroll
    for (int pi = 0; pi < 3; ++pi) {
        int p = tid * 3 + pi;
        int j = p & 63;
        float xr = v[pi * 2]     * rs * g[tid * 6 + pi * 2];
        float xi = v[pi * 2 + 1] * rs * g[tid * 6 + pi * 2 + 1];
        int rowi = (j < 22) ? (fs + fr) : ((j < 43) ? hh : ww);
        float ang = theta[rowi * 64 + j];
        float sn, cs;
        sincosf(ang, &sn, &cs);
        out[pi * 2]     = xr * cs - xi * sn;
        out[pi * 2 + 1] = xr * sn + xi * cs;
    }

    if (isQ) {
        #pragma unroll
        for (int i = 0; i < 6; ++i) row[tid * 6 + i] = out[i];
    } else {
        #pragma unroll
        for (int i = 0; i < 6; ++i) krow[tid * 6 + i] = bf16r(out[i]);
        __syncthreads();
        const int local_end = p_le[0] + (p_cs[0] + S) - p_ge[0];
        int win_start = local_end - MAX_ATTN_WIN; if (win_start < 0) win_start = 0;
        const int cpart = (local_end - S) - win_start;
        const int pos = cpart + s;
        if (pos >= 0 && tid < 192) {
            int h2 = tid >> 4, c = tid & 15;
            ushx8 u = *(const ushx8*)&krow[h2 * 128 + (c << 3)];
            *(ushx8*)&kw[(size_t)h2 * (KWROWS * HD) + (size_t)pos * HD
                         + ((c ^ (pos & 15)) << 3)] = u;
        }
    }
}

// ============ cache-only K/V pack (new rows handled by rmsnorm / gemm MODE1) ====
// y = [0,12): K head y, rows pos<cpart (cache) and pos>=L (zero).
// y = [12,24): V head y-12 transposed, same coverage as before.
__global__ __launch_bounds__(256)
void pack_kvcache_kernel(const float* __restrict__ cache_k, const float* __restrict__ cache_v,
                         ushortT* __restrict__ kw, ushortT* __restrict__ vw,
                         const int* __restrict__ p_cs, const int* __restrict__ p_ge,
                         const int* __restrict__ p_le, int S)
{
    const int kt = blockIdx.x;
    const int local_end = p_le[0] + (p_cs[0] + S) - p_ge[0];
    int win_start = local_end - MAX_ATTN_WIN; if (win_start < 0) win_start = 0;
    const int L = local_end - win_start;
    const int cpart = (local_end - S) - win_start;

    if (blockIdx.y < NHEADS) {
        const int h = blockIdx.y;
        const int tbase = kt << 6;
        if (tbase >= cpart && tbase + 64 <= L) return;   // fully rmsnorm-written
        #pragma unroll
        for (int i = 0; i < 4; ++i) {
            int cid = (i << 8) + threadIdx.x;
            int r = cid >> 4, c = cid & 15;
            int pos = tbase + r;
            if (pos >= cpart && pos < L) continue;        // rmsnorm writes these
            ushx8 u;
            if (pos < cpart) {
                const float* src = &cache_k[(size_t)(win_start + pos) * DIM + h * HD + (c << 3)];
                float4 a = *(const float4*)src;
                float4 b = *(const float4*)(src + 4);
                u = pack8(a, b);
            } else {
                #pragma unroll
                for (int j = 0; j < 8; ++j) u[j] = 0;
            }
            *(ushx8*)&kw[(size_t)h * (KWROWS * HD) + (size_t)pos * HD + ((c ^ (pos & 15)) << 3)] = u;
        }
    } else {
        const int h = blockIdx.y - NHEADS;
        const int tbase = kt << 6;
        if (tbase >= cpart && tbase + 64 <= L) return;   // fully gemm<1>-written

        __shared__ float tile[64 * 132];
        #pragma unroll
        for (int i = 0; i < 8; ++i) {
            int cid = (i << 8) + threadIdx.x;
            int r = cid >> 5, fc = cid & 31;
            int pos = tbase + r;
            float4 vv = (pos < cpart)
                ? *(const float4*)&cache_v[(size_t)(win_start + pos) * DIM + h * HD + (fc << 2)]
                : make_float4(0.f, 0.f, 0.f, 0.f);
            *(float4*)&tile[r * 132 + (fc << 2)] = vv;
        }
        __syncthreads();
        #pragma unroll
        for (int i = 0; i < 4; ++i) {
            int cid = (i << 8) + threadIdx.x;
            int d = cid >> 3, kc = cid & 7;
            int kglob = tbase + (kc << 3);
            ushx8 u;
            #pragma unroll
            for (int j = 0; j < 8; ++j)
                u[j] = bf16r(tile[((kc << 3) + j) * 132 + d]);
            size_t base = ((size_t)h * NT_MAX + kt) * TILE_ELEMS + ((size_t)d << 6)
                        + ((size_t)((kc ^ (d & 7)) << 3));
            if (kglob + 8 <= cpart) {
                *(ushx8*)&vw[base] = u;
            } else {
                #pragma unroll
                for (int j = 0; j < 8; ++j) {
                    int pos = kglob + j;
                    if (pos < cpart)      vw[base + j] = u[j];
                    else if (pos >= L)    vw[base + j] = 0;
                }
            }
        }
    }
}

// ============ MFMA flash attention v5 (proven 215 us) + trailing wo-pack blocks ===
// blocks [0, nattn): attn v5 body. blocks [nattn, nattn+gB): pack wo -> BpO,
// backfilling the ~180 free residency slots during attn (effectively free).
__global__ __launch_bounds__(256, 3)
void attn_wo_kernel(const float* __restrict__ q_lin,
                    const ushortT* __restrict__ kw, const ushortT* __restrict__ vw,
                    float* __restrict__ obuf,
                    const float* __restrict__ wo, ushortT* __restrict__ BpO,
                    const int* __restrict__ p_cs, const int* __restrict__ p_ge,
                    const int* __restrict__ p_le, int S, int nqb, int nattn)
{
    __shared__ __align__(16) ushortT Ks[TILE_ELEMS];      // 16 KB single
    __shared__ __align__(16) ushortT Vs[2][TILE_ELEMS];   // 32 KB double

    if ((int)blockIdx.x >= nattn) {
        pack_b_body(wo, BpO, ((int)blockIdx.x - nattn) * 256 + threadIdx.x);
        return;
    }

    const int tid = threadIdx.x;
    const int wid = tid >> 6, lane = tid & 63;
    const int lo = lane & 15, hi = lane >> 4;

    const int nwg = nqb * NHEADS;
    const int orig = (int)blockIdx.x;
    const int xcd = orig & 7, linb = orig >> 3;
    const int qd = nwg >> 3, rr = nwg & 7;
    const int wg = (xcd < rr ? xcd * (qd + 1) : rr * (qd + 1) + (xcd - rr) * qd) + linb;
    const int h = wg / nqb;
    const int q0 = (wg - h * nqb) << 6;

    const int local_end = p_le[0] + (p_cs[0] + S) - p_ge[0];
    int win_start = local_end - MAX_ATTN_WIN; if (win_start < 0) win_start = 0;
    const int L = local_end - win_start;
    const int ntiles = (L + 63) >> 6;

    bf16x8 aQ[4];
    {
        int q = q0 + (wid << 4) + lo;
        if (q < S) {
            const float* qp = q_lin + (size_t)q * DIM + h * HD + (hi << 3);
            #pragma unroll
            for (int ks = 0; ks < 4; ++ks) {
                float4 a = *(const float4*)&qp[ks * 32];
                float4 b = *(const float4*)&qp[ks * 32 + 4];
                ushx8 u = pack8(a, b);
                aQ[ks] = *(bf16x8*)&u;
            }
        } else {
            ushx8 z;
            #pragma unroll
            for (int j = 0; j < 8; ++j) z[j] = 0;
            #pragma unroll
            for (int ks = 0; ks < 4; ++ks) aQ[ks] = *(bf16x8*)&z;
        }
    }

    f32x4 Oa[8];
    float lsum[4];
    #pragma unroll
    for (int i = 0; i < 8; ++i) Oa[i] = (f32x4)(0.f);
    #pragma unroll
    for (int i = 0; i < 4; ++i) lsum[i] = 0.f;

    const ushortT* kwp = kw + (size_t)h * (NT_MAX * TILE_ELEMS);
    const ushortT* vwp = vw + (size_t)h * (NT_MAX * TILE_ELEMS);
    const float scale = 0.08838834764831845f;   // 1/sqrt(128)
    const int pbase = wid << 11;                // wave's own Ks quarter (2048 ush)
    const int sbase = (wid << 11) + (lane << 3);

    // prologue: stage K(0), V(0)
    #pragma unroll
    for (int i = 0; i < 4; ++i) {
        gload_lds16(kwp + sbase + (i << 9), &Ks[sbase + (i << 9)]);
        gload_lds16(vwp + sbase + (i << 9), &Vs[0][sbase + (i << 9)]);
    }

    for (int t = 0; t < ntiles; ++t) {
        const int b = t & 1;
        __syncthreads();   // A: drains own-wave K(t),V(t) DMAs; all waves synced

        // ---- S = Q K^T from Ks ----
        f32x4 Sa[4];
        #pragma unroll
        for (int nt = 0; nt < 4; ++nt) Sa[nt] = (f32x4)(0.f);
        #pragma unroll
        for (int nt = 0; nt < 4; ++nt) {
            const int kr = (nt << 4) + lo;
            #pragma unroll
            for (int ks = 0; ks < 4; ++ks) {
                bf16x8 bF = *(const bf16x8*)&Ks[kr * 128 + ((((ks << 2) + hi) ^ (kr & 15)) << 3)];
                Sa[nt] = __builtin_amdgcn_mfma_f32_16x16x32_bf16(aQ[ks], bF, Sa[nt], 0, 0, 0);
            }
        }

        __syncthreads();   // B: all waves' Ks reads done (nothing in vmcnt flight)

        // issue V(t+1) -> other half (covered by softmax+P+PV, drained at next A)
        if (t + 1 < ntiles) {
            const ushortT* vsrc = vwp + ((size_t)(t + 1) << 13);
            ushortT* vdst = &Vs[b ^ 1][0];
            #pragma unroll
            for (int i = 0; i < 4; ++i)
                gload_lds16(vsrc + sbase + (i << 9), vdst + sbase + (i << 9));
        }

        // ---- fixed-max softmax: p = exp(s*scale - 20); accumulate l ----
        const bool tail = (((t + 1) << 6) > L);
        #pragma unroll
        for (int nt = 0; nt < 4; ++nt) {
            #pragma unroll
            for (int reg = 0; reg < 4; ++reg) {
                float sv = Sa[nt][reg] * scale - 20.f;
                if (tail) {
                    int kg = (t << 6) + (nt << 4) + lo;
                    if (kg >= L) sv = -1e30f;
                }
                float p = __expf(sv);
                lsum[reg] += p;
                Sa[nt][reg] = p;
            }
        }

        // ---- P round-trip via OWN Ks quarter (same-wave DS ordered) ----
        #pragma unroll
        for (int nt = 0; nt < 4; ++nt) {
            #pragma unroll
            for (int reg = 0; reg < 4; ++reg) {
                int r = (hi << 2) + reg;
                int cc = (nt << 1) + (lo >> 3);
                Ks[pbase + (r << 6) + ((cc ^ (r & 7)) << 3) + (lo & 7)] = bf16r(Sa[nt][reg]);
            }
        }
        bf16x8 pF[2];
        #pragma unroll
        for (int ks = 0; ks < 2; ++ks)
            pF[ks] = *(const bf16x8*)&Ks[pbase + (lo << 6) + ((((ks << 2) + hi) ^ (lo & 7)) << 3)];

        // P data must be in registers before our K-DMA overwrites the quarter
        asm volatile("s_waitcnt lgkmcnt(0)" ::: "memory");
        __builtin_amdgcn_sched_barrier(0);

        // issue K(t+1) into own quarter (covered by PV, drained at next A)
        if (t + 1 < ntiles) {
            const ushortT* ksrc = kwp + ((size_t)(t + 1) << 13);
            #pragma unroll
            for (int i = 0; i < 4; ++i)
                gload_lds16(ksrc + sbase + (i << 9), &Ks[sbase + (i << 9)]);
        }

        // ---- O += P V from Vs[b] ----
        #pragma unroll
        for (int nto = 0; nto < 8; ++nto) {
            const int d = (nto << 4) + lo;
            #pragma unroll
            for (int ks = 0; ks < 2; ++ks) {
                bf16x8 vF = *(const bf16x8*)&Vs[b][(d << 6) + ((((ks << 2) + hi) ^ (d & 7)) << 3)];
                Oa[nto] = __builtin_amdgcn_mfma_f32_16x16x32_bf16(pF[ks], vF, Oa[nto], 0, 0, 0);
            }
        }
    }

    #pragma unroll
    for (int reg = 0; reg < 4; ++reg) {
        #pragma unroll
        for (int off = 1; off < 16; off <<= 1)
            lsum[reg] += __shfl_xor(lsum[reg], off, 64);
    }
    #pragma unroll
    for (int reg = 0; reg < 4; ++reg) {
        int q = q0 + (wid << 4) + (hi << 2) + reg;
        if (q < S) {
            float inv = 1.f / lsum[reg];
            #pragma unroll
            for (int nto = 0; nto < 8; ++nto)
                obuf[(size_t)q * DIM + h * HD + (nto << 4) + lo] = Oa[nto][reg] * inv;
        }
    }
}

// ==================== launch ====================
extern "C" void kernel_launch(void* const* d_in, const int* in_sizes, int n_in,
                              void* d_out, int out_size, void* d_ws, size_t ws_size,
                              hipStream_t stream)
{
    const float* x       = (const float*)d_in[0];
    const float* theta   = (const float*)d_in[1];
    const float* cache_k = (const float*)d_in[2];
    const float* cache_v = (const float*)d_in[3];
    const float* wq = (const float*)d_in[4];
    const float* bq = (const float*)d_in[5];
    const float* wk = (const float*)d_in[6];
    const float* bk = (const float*)d_in[7];
    const float* wv = (const float*)d_in[8];
    const float* bv = (const float*)d_in[9];
    const float* wo = (const float*)d_in[10];
    const float* bo = (const float*)d_in[11];
    const float* gq = (const float*)d_in[12];
    const float* gk = (const float*)d_in[13];
    const int* p_gh = (const int*)d_in[15];
    const int* p_gw = (const int*)d_in[16];
    const int* p_cs = (const int*)d_in[17];
    const int* p_ge = (const int*)d_in[18];
    const int* p_le = (const int*)d_in[19];

    const int S = in_sizes[0] / DIM;
    const int nmb = (S + 63) / 64;                   // 49
    const int Mpad = nmb * 64;

    // workspace (aliased; lifetimes stream-ordered):
    //   q_lin, k_lin (k_lin dead after rmsnorm -> o_buf alias)
    //   Ap (gemm A panels; dead after gemm_qkv -> kw aliases; Ap rewritten by
    //       pack_a AFTER attn finishes reading kw)
    //   vw, Bp0 (wq -> wo), Bp1 (wk), Bp2 (wv)
    float* q_lin = (float*)d_ws;
    float* k_lin = q_lin + (size_t)S * DIM;
    float* o_buf = k_lin;
    ushortT* Ap  = (ushortT*)(k_lin + (size_t)S * DIM);
    ushortT* kw  = Ap;                                 // alias
    ushortT* vw  = Ap + (size_t)nmb * KSTEPS * AREG;
    ushortT* Bp0 = vw + (size_t)NHEADS * NT_MAX * TILE_ELEMS;
    ushortT* Bp1 = Bp0 + (size_t)NHEADS * KSTEPS * BREG;
    ushortT* Bp2 = Bp1 + (size_t)NHEADS * KSTEPS * BREG;

    dim3 blk(256);
    const int nwgG = nmb * (DIM / 128);                // 588
    const int gA = (Mpad * 192) / 256;                 // 2352
    const int gB = (DIM * 192) / 256;                  // 1152

    pack_all_kernel<<<gA + 3 * gB, blk, 0, stream>>>(x, wq, wk, wv,
                                                     Ap, Bp0, Bp1, Bp2, S, gA, gB);
    gemm_qkv_kernel<<<3 * nwgG, blk, 0, stream>>>(Ap, Bp0, Bp1, Bp2, bq, bk, bv,
                                                  q_lin, k_lin, vw, S, nmb, nwgG,
                                                  p_cs, p_ge, p_le);

    rmsnorm_rope_kernel<<<dim3(S, 2), blk, 0, stream>>>(q_lin, k_lin, kw, gq, gk, theta,
                                                        p_gh, p_gw, p_cs, p_ge, p_le, S);

    pack_kvcache_kernel<<<dim3(NT_MAX, 2 * NHEADS), blk, 0, stream>>>(
        cache_k, cache_v, kw, vw, p_cs, p_ge, p_le, S);

    const int nqb = (S + 63) / 64;                     // 49 -> 588 attn blocks
    attn_wo_kernel<<<dim3(nqb * NHEADS + gB), blk, 0, stream>>>(
        q_lin, kw, vw, o_buf, wo, Bp0, p_cs, p_ge, p_le, S, nqb, nqb * NHEADS);

    pack_a_kernel<<<gA, blk, 0, stream>>>(o_buf, Ap, S, Mpad);
    gemm_single_kernel<0><<<nwgG, blk, 0, stream>>>(Ap, Bp0, bo, (float*)d_out, nullptr,
                                                    S, nmb, p_cs, p_ge, p_le);
}